// Round 5
// baseline (237.592 us; speedup 1.0000x reference)
//
#include <hip/hip_runtime.h>

#define BINS 10
#define TPB 256
#define MAX_BLOCKS 2048   // 8 blocks/CU * 256 CU; grid-stride covers N
#define NTHR 9            // bin thresholds k=1..9 in u-space
#define CH 4              // float4 iterations batched per load-then-compute chunk
#define ACC_N (BINS + NTHR)   // 19 global accumulators
#define POISON 0xAAAAAAAAu    // harness re-poisons d_ws to 0xAA bytes each call

// u-space bin boundaries: c_k = ln(k / (9.9999 - k))  (logit of k/9.9999).
// bin(sigmoid(u)) >= k  <=>  u >= c_k   (sigmoid monotone).
__device__ __constant__ const float c_thr[NTHR] = {
    -2.1972135f, -1.3862819f, -0.8472836f, -0.4054484f, 2.00002e-5f,
     0.4054901f,  0.8473312f,  1.3863444f,  2.1973246f
};

// Register-resident suffix-histogram accumulate.
// A[0]  += ce (total);  A[k] += ce*(u>=c_k);  C[k-1] += (u>=c_k), k=1..9.
__device__ __forceinline__ void ghmc_accum(float z, int t, float* A, float* C) {
    // t in {0,1}:  g = |sigmoid(z)-t| = sigmoid(u),  ce = softplus(u),
    // with u = (t ? -z : z) = z with sign bit xor'd by t.
    unsigned ub = __float_as_uint(z) ^ ((unsigned)t << 31);
    float u  = __uint_as_float(ub);
    float e  = __expf(-fabsf(u));                  // v_mul + v_exp
    float q  = 1.0f + e;
    float ce = fmaxf(u, 0.0f) + __logf(q);         // v_max + v_log(+mul) + v_add
    A[0] += ce;
    #pragma unroll
    for (int k = 1; k <= NTHR; ++k) {
        float m = (u >= c_thr[k - 1]) ? 1.0f : 0.0f;  // v_cmp + v_cndmask
        A[k]    = fmaf(m, ce, A[k]);                  // v_fma
        C[k - 1] += m;                                // v_add
    }
}

// Fully fused: streaming suffix-histogram + last-block finalize.
// ws layout: wsf[0..9]=A suffix ce-sums, wsf[10..18]=C suffix counts,
//            ((unsigned*)wsf)[19] = arrival counter (starts at POISON).
__global__ __launch_bounds__(TPB, 4) void ghmc_fused(const float* __restrict__ x,
                                                     const int* __restrict__ tgt,
                                                     float* __restrict__ wsf,
                                                     float* __restrict__ out,
                                                     int nvec, int ntotal, int nblocks) {
    float A[BINS];   // A[0]=total ce, A[k]=suffix ce-sum for threshold k
    float C[NTHR];   // suffix counts for thresholds 1..9
    #pragma unroll
    for (int b = 0; b < BINS; ++b) A[b] = 0.0f;
    #pragma unroll
    for (int k = 0; k < NTHR; ++k) C[k] = 0.0f;

    const float4* __restrict__ x4 = (const float4*)x;
    const int4*  __restrict__ t4 = (const int4*)tgt;
    const int tid = threadIdx.x;
    const int stride = gridDim.x * TPB;
    const int nfull  = nvec / stride;          // = 8 for N=2^24, 2048 blocks
    const int nchunk = nfull / CH;             // = 2
    int gi = blockIdx.x * TPB + tid;

    for (int c = 0; c < nchunk; ++c) {
        float4 xv[CH];
        int4   tv[CH];
        // Issue all 2*CH = 8 global_load_dwordx4 back-to-back.
        #pragma unroll
        for (int j = 0; j < CH; ++j) {
            xv[j] = x4[gi + j * stride];
            tv[j] = t4[gi + j * stride];
        }
        // Hard fence: scheduler may NOT sink these loads into the compute
        // below (round-4's unfenced version was re-paced by regalloc).
        __builtin_amdgcn_sched_barrier(0);
        gi += CH * stride;
        #pragma unroll
        for (int j = 0; j < CH; ++j) {
            ghmc_accum(xv[j].x, tv[j].x, A, C);
            ghmc_accum(xv[j].y, tv[j].y, A, C);
            ghmc_accum(xv[j].z, tv[j].z, A, C);
            ghmc_accum(xv[j].w, tv[j].w, A, C);
        }
    }
    // Leftover full iterations (nfull % CH) — no-op for N = 2^24.
    for (int it = nchunk * CH; it < nfull; ++it, gi += stride) {
        float4 xv = x4[gi];
        int4   tv = t4[gi];
        ghmc_accum(xv.x, tv.x, A, C);
        ghmc_accum(xv.y, tv.y, A, C);
        ghmc_accum(xv.z, tv.z, A, C);
        ghmc_accum(xv.w, tv.w, A, C);
    }
    // Residual vec4 elements (nvec % stride) — no-op for N = 2^24.
    if (gi < nvec) {
        float4 xv = x4[gi];
        int4   tv = t4[gi];
        ghmc_accum(xv.x, tv.x, A, C);
        ghmc_accum(xv.y, tv.y, A, C);
        ghmc_accum(xv.z, tv.z, A, C);
        ghmc_accum(xv.w, tv.w, A, C);
    }
    // Scalar tail (N not a multiple of 4) — no-op for N = 2^24.
    if (blockIdx.x == 0) {
        for (int i = nvec * 4 + tid; i < ntotal; i += TPB)
            ghmc_accum(x[i], tgt[i], A, C);
    }

    // Wave-level shuffle reduce, then tiny LDS combine of the 4 waves.
    #pragma unroll
    for (int b = 0; b < BINS; ++b) {
        #pragma unroll
        for (int o = 32; o > 0; o >>= 1) A[b] += __shfl_down(A[b], o);
    }
    #pragma unroll
    for (int k = 0; k < NTHR; ++k) {
        #pragma unroll
        for (int o = 32; o > 0; o >>= 1) C[k] += __shfl_down(C[k], o);
    }
    __shared__ float red[TPB / 64][2 * BINS];   // 320 B
    const int wid = tid >> 6, lane = tid & 63;
    if (lane == 0) {
        #pragma unroll
        for (int b = 0; b < BINS; ++b) red[wid][b] = A[b];
        #pragma unroll
        for (int k = 0; k < NTHR; ++k) red[wid][BINS + k] = C[k];
    }
    __syncthreads();

    // Per-block result -> device-scope atomics (coherent across XCDs).
    // Poison bias on accumulators is -3.03e-13 — rounds away against O(1e3+) partials.
    if (tid < ACC_N) {
        float v = 0.0f;
        #pragma unroll
        for (int w = 0; w < TPB / 64; ++w) v += red[w][tid];
        atomicAdd(&wsf[tid], v);
    }
    __syncthreads();   // all 19 atomics of this block complete before arrival

    int lastf = 0;
    if (tid == 0) {
        __threadfence();   // release: our adds visible before the arrival tick
        unsigned old = atomicAdd((unsigned*)&wsf[ACC_N], 1u);
        unsigned nb1 = (unsigned)nblocks - 1u;
        lastf = (old - POISON == nb1) || (old == nb1);   // poison or zero base
    }
    lastf = __shfl(lastf, 0);          // wave-0 broadcast (other waves get 0)
    if (lastf) {
        __threadfence();               // acquire side
        // Parallel coherent read-back of the 19 accumulators.
        float rv = (tid < ACC_N) ? atomicAdd(&wsf[tid], 0.0f) : 0.0f;
        if (tid < ACC_N) red[0][tid] = rv;   // same wave: no barrier needed
        if (tid == 0) {
            float Af[BINS + 1], Cf[BINS + 1];
            #pragma unroll
            for (int b = 0; b < BINS; ++b) Af[b] = red[0][b];
            Af[BINS] = 0.0f;
            Cf[0] = (float)ntotal;     // exact: ntotal <= 2^24
            #pragma unroll
            for (int k = 1; k <= NTHR; ++k) Cf[k] = red[0][BINS + k - 1];
            Cf[BINS] = 0.0f;
            float ne = 0.0f;
            #pragma unroll
            for (int b = 0; b < BINS; ++b) {
                float c = Cf[b] - Cf[b + 1];
                ne += (c > 0.0f) ? 1.0f : 0.0f;
            }
            float res = 0.0f;
            #pragma unroll
            for (int b = 0; b < BINS; ++b) {
                float s = Af[b] - Af[b + 1];
                float c = Cf[b] - Cf[b + 1];
                res += s / fmaxf(c * ne, 1e-6f);
            }
            out[0] = res;
        }
    }
}

extern "C" void kernel_launch(void* const* d_in, const int* in_sizes, int n_in,
                              void* d_out, int out_size, void* d_ws, size_t ws_size,
                              hipStream_t stream) {
    const float* x   = (const float*)d_in[0];
    const int*   tgt = (const int*)d_in[1];
    float* out = (float*)d_out;
    float* wsf = (float*)d_ws;

    int N    = in_sizes[0];
    int nvec = N / 4;

    int blocks = MAX_BLOCKS;
    int need = (nvec + TPB - 1) / TPB;
    if (blocks > need) blocks = need;
    if (blocks < 1) blocks = 1;

    ghmc_fused<<<blocks, TPB, 0, stream>>>(x, tgt, wsf, out, nvec, N, blocks);
}

// Round 6
// 152.782 us; speedup vs baseline: 1.5551x; 1.5551x over previous
//
#include <hip/hip_runtime.h>

#define BINS 10
#define TPB 256
#define MAX_BLOCKS 2048   // 8 blocks/CU * 256 CU; grid-stride covers N
#define NTHR 9            // bin thresholds k=1..9 in u-space
#define DEPTH 4           // forced in-flight load pairs per wave

typedef float f32x4 __attribute__((ext_vector_type(4)));
typedef int   i32x4 __attribute__((ext_vector_type(4)));

// u-space bin boundaries: c_k = ln(k / (9.9999 - k))  (logit of k/9.9999).
// bin(sigmoid(u)) >= k  <=>  u >= c_k   (sigmoid monotone).
__device__ __constant__ const float c_thr[NTHR] = {
    -2.1972135f, -1.3862819f, -0.8472836f, -0.4054484f, 2.00002e-5f,
     0.4054901f,  0.8473312f,  1.3863444f,  2.1973246f
};

// Register-resident suffix-histogram accumulate.
// A[0]  += ce (total);  A[k] += ce*(u>=c_k);  C[k-1] += (u>=c_k), k=1..9.
__device__ __forceinline__ void ghmc_accum(float z, int t, float* A, float* C) {
    // t in {0,1}:  g = |sigmoid(z)-t| = sigmoid(u),  ce = softplus(u),
    // with u = (t ? -z : z) = z with sign bit xor'd by t.
    unsigned ub = __float_as_uint(z) ^ ((unsigned)t << 31);
    float u  = __uint_as_float(ub);
    float e  = __expf(-fabsf(u));                  // v_mul + v_exp
    float q  = 1.0f + e;
    float ce = fmaxf(u, 0.0f) + __logf(q);         // v_max + v_log(+mul) + v_add
    A[0] += ce;
    #pragma unroll
    for (int k = 1; k <= NTHR; ++k) {
        float m = (u >= c_thr[k - 1]) ? 1.0f : 0.0f;  // v_cmp + v_cndmask
        A[k]    = fmaf(m, ce, A[k]);                  // v_fma
        C[k - 1] += m;                                // v_add
    }
}

// Inline-asm load pair: invisible to the compiler's waitcnt pass, so it
// cannot insert a pipeline-collapsing vmcnt(0); we count waits by hand.
#define ISSUE(xs, ts, idx) do {                                   \
    const f32x4* _xa = x4 + (idx);                                \
    const i32x4* _ta = t4 + (idx);                                \
    asm volatile("global_load_dwordx4 %0, %2, off\n\t"            \
                 "global_load_dwordx4 %1, %3, off"                \
                 : "=&v"(xs), "=&v"(ts)                           \
                 : "v"(_xa), "v"(_ta)                             \
                 : "memory");                                     \
} while (0)

#define COMPUTE(xs, ts) do {                                      \
    ghmc_accum((xs).x, (ts).x, A, C);                             \
    ghmc_accum((xs).y, (ts).y, A, C);                             \
    ghmc_accum((xs).z, (ts).z, A, C);                             \
    ghmc_accum((xs).w, (ts).w, A, C);                             \
} while (0)

// Counted wait + rule-#18 fence (compute must not hoist above the wait).
#define WAITV(n) do {                                             \
    asm volatile("s_waitcnt vmcnt(" #n ")" ::: "memory");         \
    __builtin_amdgcn_sched_barrier(0);                            \
} while (0)

__global__ __launch_bounds__(TPB, 4) void ghmc_main(const float* __restrict__ x,
                                                    const int* __restrict__ tgt,
                                                    float* __restrict__ partial,  // [gridDim.x][2*BINS]
                                                    int nvec, int ntotal) {
    float A[BINS];   // A[0]=total ce, A[k]=suffix ce-sum for threshold k
    float C[NTHR];   // suffix counts for thresholds 1..9
    #pragma unroll
    for (int b = 0; b < BINS; ++b) A[b] = 0.0f;
    #pragma unroll
    for (int k = 0; k < NTHR; ++k) C[k] = 0.0f;

    const f32x4* __restrict__ x4 = (const f32x4*)x;
    const i32x4* __restrict__ t4 = (const i32x4*)tgt;
    const int tid = threadIdx.x;
    const int stride = gridDim.x * TPB;
    const int nfull  = nvec / stride;          // = 8 for N=2^24, 2048 blocks
    const int gi0 = blockIdx.x * TPB + tid;
    int it_done = 0;

    if (nfull >= DEPTH) {
        // Depth-4 software pipeline, 4 static slots (rule #20: no runtime
        // indexing -> slots stay in VGPRs). Issue order is [s0,s0,s1,s1,...],
        // so vmcnt(6) before compute of slot s guarantees s's pair landed;
        // reissue-after-compute keeps outstanding <= 8 (constant vmcnt(6)).
        f32x4 xs0, xs1, xs2, xs3;
        i32x4 ts0, ts1, ts2, ts3;
        int gp = gi0;
        ISSUE(xs0, ts0, gp); gp += stride;
        ISSUE(xs1, ts1, gp); gp += stride;
        ISSUE(xs2, ts2, gp); gp += stride;
        ISSUE(xs3, ts3, gp); gp += stride;
        const int nchunk = nfull / DEPTH;      // >= 1 here
        for (int c = 0; c < nchunk - 1; ++c) {
            WAITV(6); COMPUTE(xs0, ts0); ISSUE(xs0, ts0, gp); gp += stride;
            WAITV(6); COMPUTE(xs1, ts1); ISSUE(xs1, ts1, gp); gp += stride;
            WAITV(6); COMPUTE(xs2, ts2); ISSUE(xs2, ts2, gp); gp += stride;
            WAITV(6); COMPUTE(xs3, ts3); ISSUE(xs3, ts3, gp); gp += stride;
        }
        // Epilogue chunk: drain 6 -> 4 -> 2 -> 0 (never vmcnt(0) in the loop).
        WAITV(6); COMPUTE(xs0, ts0);
        WAITV(4); COMPUTE(xs1, ts1);
        WAITV(2); COMPUTE(xs2, ts2);
        WAITV(0); COMPUTE(xs3, ts3);
        it_done = nchunk * DEPTH;
    }
    // Leftover full iterations (nfull % DEPTH, plus the nfull<DEPTH case).
    for (int it = it_done; it < nfull; ++it) {
        int g = gi0 + it * stride;
        f32x4 xv = x4[g];
        i32x4 tv = t4[g];
        COMPUTE(xv, tv);
    }
    // Residual vec4 elements (nvec % stride) — no-op for N = 2^24.
    {
        int gr = gi0 + nfull * stride;
        if (gr < nvec) {
            f32x4 xv = x4[gr];
            i32x4 tv = t4[gr];
            COMPUTE(xv, tv);
        }
    }
    // Scalar tail (N not a multiple of 4) — no-op for N = 2^24.
    if (blockIdx.x == 0) {
        for (int i = nvec * 4 + tid; i < ntotal; i += TPB)
            ghmc_accum(x[i], tgt[i], A, C);
    }

    // Wave-level shuffle reduce (64 lanes), then tiny LDS combine of the 4 waves.
    #pragma unroll
    for (int b = 0; b < BINS; ++b) {
        #pragma unroll
        for (int o = 32; o > 0; o >>= 1) A[b] += __shfl_down(A[b], o);
    }
    #pragma unroll
    for (int k = 0; k < NTHR; ++k) {
        #pragma unroll
        for (int o = 32; o > 0; o >>= 1) C[k] += __shfl_down(C[k], o);
    }
    __shared__ float red[TPB / 64][2 * BINS];   // 320 B — no occupancy impact
    const int wid = tid >> 6, lane = tid & 63;
    if (lane == 0) {
        #pragma unroll
        for (int b = 0; b < BINS; ++b) red[wid][b] = A[b];
        #pragma unroll
        for (int k = 0; k < NTHR; ++k) red[wid][BINS + k] = C[k];
    }
    __syncthreads();
    if (tid < BINS + NTHR) {
        float v = 0.0f;
        #pragma unroll
        for (int w = 0; w < TPB / 64; ++w) v += red[w][tid];
        partial[blockIdx.x * (2 * BINS) + tid] = v;   // per-block partials: no atomics
    }
}

// Recover per-bin sums/counts from suffix accumulators, then
// result = sum_b sum_ce_b / max(cnt_b * nonempty, 1e-6)   (the N in beta cancels)
__global__ __launch_bounds__(TPB) void ghmc_final(const float* __restrict__ partial,
                                                  float* __restrict__ out,
                                                  int nblocks, int ntotal) {
    float acc[2 * BINS];
    #pragma unroll
    for (int k = 0; k < 2 * BINS; ++k) acc[k] = 0.0f;
    for (int row = threadIdx.x; row < nblocks; row += TPB) {
        const float* p = partial + row * (2 * BINS);
        #pragma unroll
        for (int k = 0; k < 2 * BINS; ++k) acc[k] += p[k];
    }
    #pragma unroll
    for (int k = 0; k < 2 * BINS; ++k) {
        #pragma unroll
        for (int o = 32; o > 0; o >>= 1) acc[k] += __shfl_down(acc[k], o);
    }
    __shared__ float red[TPB / 64][2 * BINS];
    const int wid = threadIdx.x >> 6, lane = threadIdx.x & 63;
    if (lane == 0) {
        #pragma unroll
        for (int k = 0; k < 2 * BINS; ++k) red[wid][k] = acc[k];
    }
    __syncthreads();
    if (threadIdx.x == 0) {
        float A[BINS + 1], C[BINS + 1];
        #pragma unroll
        for (int b = 0; b < BINS; ++b) {
            float v = 0.0f;
            #pragma unroll
            for (int w = 0; w < TPB / 64; ++w) v += red[w][b];
            A[b] = v;
        }
        A[BINS] = 0.0f;
        C[0] = (float)ntotal;          // exact: ntotal <= 2^24
        #pragma unroll
        for (int k = 1; k <= NTHR; ++k) {
            float v = 0.0f;
            #pragma unroll
            for (int w = 0; w < TPB / 64; ++w) v += red[w][BINS + k - 1];
            C[k] = v;
        }
        C[BINS] = 0.0f;
        float ne = 0.0f;
        #pragma unroll
        for (int b = 0; b < BINS; ++b) {
            float c = C[b] - C[b + 1];
            ne += (c > 0.0f) ? 1.0f : 0.0f;
        }
        float res = 0.0f;
        #pragma unroll
        for (int b = 0; b < BINS; ++b) {
            float s = A[b] - A[b + 1];
            float c = C[b] - C[b + 1];
            res += s / fmaxf(c * ne, 1e-6f);
        }
        out[0] = res;
    }
}

extern "C" void kernel_launch(void* const* d_in, const int* in_sizes, int n_in,
                              void* d_out, int out_size, void* d_ws, size_t ws_size,
                              hipStream_t stream) {
    const float* x   = (const float*)d_in[0];
    const int*   tgt = (const int*)d_in[1];
    float* out     = (float*)d_out;
    float* partial = (float*)d_ws;

    int N    = in_sizes[0];
    int nvec = N / 4;

    int blocks = MAX_BLOCKS;
    int maxrows = (int)(ws_size / (2 * BINS * sizeof(float)));   // stay inside workspace
    if (blocks > maxrows) blocks = maxrows;
    int need = (nvec + TPB - 1) / TPB;
    if (blocks > need) blocks = need;
    if (blocks < 1) blocks = 1;

    ghmc_main<<<blocks, TPB, 0, stream>>>(x, tgt, partial, nvec, N);
    ghmc_final<<<1, TPB, 0, stream>>>(partial, out, blocks, N);
}

// Round 7
// 148.922 us; speedup vs baseline: 1.5954x; 1.0259x over previous
//
#include <hip/hip_runtime.h>

#define BINS 10
#define TPB 256
#define MAX_BLOCKS 512    // 2 blocks/CU: long per-wave streams -> deep pipeline amortizes
#define NTHR 9            // bin thresholds k=1..9 in u-space
#define DEPTH 8           // forced in-flight load pairs per wave (16 loads)

typedef float f32x4 __attribute__((ext_vector_type(4)));
typedef int   i32x4 __attribute__((ext_vector_type(4)));

// u-space bin boundaries: c_k = ln(k / (9.9999 - k))  (logit of k/9.9999).
// bin(sigmoid(u)) >= k  <=>  u >= c_k   (sigmoid monotone).
__device__ __constant__ const float c_thr[NTHR] = {
    -2.1972135f, -1.3862819f, -0.8472836f, -0.4054484f, 2.00002e-5f,
     0.4054901f,  0.8473312f,  1.3863444f,  2.1973246f
};

// Register-resident suffix-histogram accumulate.
// A[0]  += ce (total);  A[k] += ce*(u>=c_k);  C[k-1] += (u>=c_k), k=1..9.
__device__ __forceinline__ void ghmc_accum(float z, int t, float* A, float* C) {
    // t in {0,1}:  g = |sigmoid(z)-t| = sigmoid(u),  ce = softplus(u),
    // with u = (t ? -z : z) = z with sign bit xor'd by t.
    unsigned ub = __float_as_uint(z) ^ ((unsigned)t << 31);
    float u  = __uint_as_float(ub);
    float e  = __expf(-fabsf(u));                  // v_mul + v_exp
    float q  = 1.0f + e;
    float ce = fmaxf(u, 0.0f) + __logf(q);         // v_max + v_log(+mul) + v_add
    A[0] += ce;
    #pragma unroll
    for (int k = 1; k <= NTHR; ++k) {
        float m = (u >= c_thr[k - 1]) ? 1.0f : 0.0f;  // v_cmp + v_cndmask
        A[k]    = fmaf(m, ce, A[k]);                  // v_fma
        C[k - 1] += m;                                // v_add
    }
}

// Inline-asm load pair: invisible to the compiler's waitcnt pass, so it
// cannot insert a pipeline-collapsing vmcnt(0); we count waits by hand.
#define ISSUE(xs, ts, idx) do {                                   \
    const f32x4* _xa = x4 + (idx);                                \
    const i32x4* _ta = t4 + (idx);                                \
    asm volatile("global_load_dwordx4 %0, %2, off\n\t"            \
                 "global_load_dwordx4 %1, %3, off"                \
                 : "=&v"(xs), "=&v"(ts)                           \
                 : "v"(_xa), "v"(_ta)                             \
                 : "memory");                                     \
} while (0)

#define COMPUTE(xs, ts) do {                                      \
    ghmc_accum((xs).x, (ts).x, A, C);                             \
    ghmc_accum((xs).y, (ts).y, A, C);                             \
    ghmc_accum((xs).z, (ts).z, A, C);                             \
    ghmc_accum((xs).w, (ts).w, A, C);                             \
} while (0)

// Counted wait + rule-#18 fence (compute must not hoist above the wait).
#define WAITV(n) do {                                             \
    asm volatile("s_waitcnt vmcnt(" #n ")" ::: "memory");         \
    __builtin_amdgcn_sched_barrier(0);                            \
} while (0)

__global__ __launch_bounds__(TPB, 2) void ghmc_main(const float* __restrict__ x,
                                                    const int* __restrict__ tgt,
                                                    float* __restrict__ partial,  // [gridDim.x][2*BINS]
                                                    int nvec, int ntotal) {
    float A[BINS];   // A[0]=total ce, A[k]=suffix ce-sum for threshold k
    float C[NTHR];   // suffix counts for thresholds 1..9
    #pragma unroll
    for (int b = 0; b < BINS; ++b) A[b] = 0.0f;
    #pragma unroll
    for (int k = 0; k < NTHR; ++k) C[k] = 0.0f;

    const f32x4* __restrict__ x4 = (const f32x4*)x;
    const i32x4* __restrict__ t4 = (const i32x4*)tgt;
    const int tid = threadIdx.x;
    const int stride = gridDim.x * TPB;
    const int nfull  = nvec / stride;          // = 32 for N=2^24, 512 blocks
    const int gi0 = blockIdx.x * TPB + tid;
    int it_done = 0;

    if (nfull >= DEPTH) {
        // Depth-8 software pipeline, 8 static slots (rule #20: no runtime
        // indexing -> slots stay in VGPRs). Issue order [s0,s0,s1,s1,...];
        // vmcnt(14) before slot s's compute guarantees s's pair landed;
        // reissue-after-compute keeps outstanding at 16 (7 compute phases
        // ~2800 cy between a slot's issue and its wait >> ~900 cy HBM).
        f32x4 xs0, xs1, xs2, xs3, xs4, xs5, xs6, xs7;
        i32x4 ts0, ts1, ts2, ts3, ts4, ts5, ts6, ts7;
        int gp = gi0;
        ISSUE(xs0, ts0, gp); gp += stride;
        ISSUE(xs1, ts1, gp); gp += stride;
        ISSUE(xs2, ts2, gp); gp += stride;
        ISSUE(xs3, ts3, gp); gp += stride;
        ISSUE(xs4, ts4, gp); gp += stride;
        ISSUE(xs5, ts5, gp); gp += stride;
        ISSUE(xs6, ts6, gp); gp += stride;
        ISSUE(xs7, ts7, gp); gp += stride;
        const int nchunk = nfull / DEPTH;      // = 4 for N=2^24
        for (int c = 0; c < nchunk - 1; ++c) {
            WAITV(14); COMPUTE(xs0, ts0); ISSUE(xs0, ts0, gp); gp += stride;
            WAITV(14); COMPUTE(xs1, ts1); ISSUE(xs1, ts1, gp); gp += stride;
            WAITV(14); COMPUTE(xs2, ts2); ISSUE(xs2, ts2, gp); gp += stride;
            WAITV(14); COMPUTE(xs3, ts3); ISSUE(xs3, ts3, gp); gp += stride;
            WAITV(14); COMPUTE(xs4, ts4); ISSUE(xs4, ts4, gp); gp += stride;
            WAITV(14); COMPUTE(xs5, ts5); ISSUE(xs5, ts5, gp); gp += stride;
            WAITV(14); COMPUTE(xs6, ts6); ISSUE(xs6, ts6, gp); gp += stride;
            WAITV(14); COMPUTE(xs7, ts7); ISSUE(xs7, ts7, gp); gp += stride;
        }
        // Drain: 14 -> 12 -> ... -> 0 (never vmcnt(0) inside the loop).
        WAITV(14); COMPUTE(xs0, ts0);
        WAITV(12); COMPUTE(xs1, ts1);
        WAITV(10); COMPUTE(xs2, ts2);
        WAITV(8);  COMPUTE(xs3, ts3);
        WAITV(6);  COMPUTE(xs4, ts4);
        WAITV(4);  COMPUTE(xs5, ts5);
        WAITV(2);  COMPUTE(xs6, ts6);
        WAITV(0);  COMPUTE(xs7, ts7);
        it_done = nchunk * DEPTH;
    }
    // Leftover full iterations (nfull % DEPTH, plus the nfull<DEPTH case).
    for (int it = it_done; it < nfull; ++it) {
        int g = gi0 + it * stride;
        f32x4 xv = x4[g];
        i32x4 tv = t4[g];
        COMPUTE(xv, tv);
    }
    // Residual vec4 elements (nvec % stride) — no-op for N = 2^24.
    {
        int gr = gi0 + nfull * stride;
        if (gr < nvec) {
            f32x4 xv = x4[gr];
            i32x4 tv = t4[gr];
            COMPUTE(xv, tv);
        }
    }
    // Scalar tail (N not a multiple of 4) — no-op for N = 2^24.
    if (blockIdx.x == 0) {
        for (int i = nvec * 4 + tid; i < ntotal; i += TPB)
            ghmc_accum(x[i], tgt[i], A, C);
    }

    // Wave-level shuffle reduce (64 lanes), then tiny LDS combine of the 4 waves.
    #pragma unroll
    for (int b = 0; b < BINS; ++b) {
        #pragma unroll
        for (int o = 32; o > 0; o >>= 1) A[b] += __shfl_down(A[b], o);
    }
    #pragma unroll
    for (int k = 0; k < NTHR; ++k) {
        #pragma unroll
        for (int o = 32; o > 0; o >>= 1) C[k] += __shfl_down(C[k], o);
    }
    __shared__ float red[TPB / 64][2 * BINS];   // 320 B — no occupancy impact
    const int wid = tid >> 6, lane = tid & 63;
    if (lane == 0) {
        #pragma unroll
        for (int b = 0; b < BINS; ++b) red[wid][b] = A[b];
        #pragma unroll
        for (int k = 0; k < NTHR; ++k) red[wid][BINS + k] = C[k];
    }
    __syncthreads();
    if (tid < BINS + NTHR) {
        float v = 0.0f;
        #pragma unroll
        for (int w = 0; w < TPB / 64; ++w) v += red[w][tid];
        partial[blockIdx.x * (2 * BINS) + tid] = v;   // per-block partials: no atomics
    }
}

// Recover per-bin sums/counts from suffix accumulators, then
// result = sum_b sum_ce_b / max(cnt_b * nonempty, 1e-6)   (the N in beta cancels)
__global__ __launch_bounds__(TPB) void ghmc_final(const float* __restrict__ partial,
                                                  float* __restrict__ out,
                                                  int nblocks, int ntotal) {
    float acc[2 * BINS];
    #pragma unroll
    for (int k = 0; k < 2 * BINS; ++k) acc[k] = 0.0f;
    for (int row = threadIdx.x; row < nblocks; row += TPB) {
        const float* p = partial + row * (2 * BINS);
        #pragma unroll
        for (int k = 0; k < 2 * BINS; ++k) acc[k] += p[k];
    }
    #pragma unroll
    for (int k = 0; k < 2 * BINS; ++k) {
        #pragma unroll
        for (int o = 32; o > 0; o >>= 1) acc[k] += __shfl_down(acc[k], o);
    }
    __shared__ float red[TPB / 64][2 * BINS];
    const int wid = threadIdx.x >> 6, lane = threadIdx.x & 63;
    if (lane == 0) {
        #pragma unroll
        for (int k = 0; k < 2 * BINS; ++k) red[wid][k] = acc[k];
    }
    __syncthreads();
    if (threadIdx.x == 0) {
        float A[BINS + 1], C[BINS + 1];
        #pragma unroll
        for (int b = 0; b < BINS; ++b) {
            float v = 0.0f;
            #pragma unroll
            for (int w = 0; w < TPB / 64; ++w) v += red[w][b];
            A[b] = v;
        }
        A[BINS] = 0.0f;
        C[0] = (float)ntotal;          // exact: ntotal <= 2^24
        #pragma unroll
        for (int k = 1; k <= NTHR; ++k) {
            float v = 0.0f;
            #pragma unroll
            for (int w = 0; w < TPB / 64; ++w) v += red[w][BINS + k - 1];
            C[k] = v;
        }
        C[BINS] = 0.0f;
        float ne = 0.0f;
        #pragma unroll
        for (int b = 0; b < BINS; ++b) {
            float c = C[b] - C[b + 1];
            ne += (c > 0.0f) ? 1.0f : 0.0f;
        }
        float res = 0.0f;
        #pragma unroll
        for (int b = 0; b < BINS; ++b) {
            float s = A[b] - A[b + 1];
            float c = C[b] - C[b + 1];
            res += s / fmaxf(c * ne, 1e-6f);
        }
        out[0] = res;
    }
}

extern "C" void kernel_launch(void* const* d_in, const int* in_sizes, int n_in,
                              void* d_out, int out_size, void* d_ws, size_t ws_size,
                              hipStream_t stream) {
    const float* x   = (const float*)d_in[0];
    const int*   tgt = (const int*)d_in[1];
    float* out     = (float*)d_out;
    float* partial = (float*)d_ws;

    int N    = in_sizes[0];
    int nvec = N / 4;

    int blocks = MAX_BLOCKS;
    int maxrows = (int)(ws_size / (2 * BINS * sizeof(float)));   // stay inside workspace
    if (blocks > maxrows) blocks = maxrows;
    int need = (nvec + TPB - 1) / TPB;
    if (blocks > need) blocks = need;
    if (blocks < 1) blocks = 1;

    ghmc_main<<<blocks, TPB, 0, stream>>>(x, tgt, partial, nvec, N);
    ghmc_final<<<1, TPB, 0, stream>>>(partial, out, blocks, N);
}